// Round 1
// baseline (122.279 us; speedup 1.0000x reference)
//
#include <hip/hip_runtime.h>
#include <hip/hip_bf16.h>
#include <math.h>

// MultibandFrameAttention: B=4, W=1024, C=512, H=8, D=64
// Pipeline: er-transpose | qkv proj GEMM (bf16 MFMA) | dwconv (qk + v-transposed)
//           | flash attention with relative-position term | output GEMM.
// pos[i,j] = q_j . er[:,i]  => S_tile += mfma(A=erT rows I, B=Q rows J)

#define CROP 1024
#define NB 512
#define NH 8
#define HD 64
#define NBATCH 4
#define MTOT 4096

typedef __attribute__((ext_vector_type(8))) short bf8;
typedef __attribute__((ext_vector_type(4))) float f4;

__device__ __forceinline__ short f2bf(float f) {
  union { float f; unsigned u; } v; v.f = f;
  unsigned r = (v.u + 0x7fffu + ((v.u >> 16) & 1u)) >> 16;
  return (short)r;
}
__device__ __forceinline__ float bf2f(short s) {
  union { unsigned u; float f; } v; v.u = ((unsigned)(unsigned short)s) << 16;
  return v.f;
}
__device__ __forceinline__ f4 mfma16(bf8 a, bf8 b, f4 c) {
  return __builtin_amdgcn_mfma_f32_16x16x32_bf16(a, b, c, 0, 0, 0);
}

// ---------------- er transpose: erT[w][d] = bf16(er[d][w]) ----------------
__global__ void ert_kernel(const float* __restrict__ er, short* __restrict__ erT) {
  int idx = blockIdx.x * 256 + threadIdx.x;  // 0 .. 64*1024-1
  if (idx >= HD * CROP) return;
  int w = idx >> 6, d = idx & 63;
  erT[idx] = f2bf(er[d * CROP + w]);
}

// ---------------- QKV projection GEMM: C[m,n] = sum_k X[m,k]*W[n,k] + b[n] ----------------
__global__ __launch_bounds__(256) void proj_gemm(
    const float* __restrict__ X,
    const float* __restrict__ W0, const float* __restrict__ B0,
    const float* __restrict__ W1, const float* __restrict__ B1,
    const float* __restrict__ W2, const float* __restrict__ B2,
    short* __restrict__ O0, short* __restrict__ O1, short* __restrict__ O2)
{
  const int p = blockIdx.z;
  const float* Wt = (p == 0) ? W0 : (p == 1) ? W1 : W2;
  const float* Bb = (p == 0) ? B0 : (p == 1) ? B1 : B2;
  short* Out = (p == 0) ? O0 : (p == 1) ? O1 : O2;

  __shared__ short As[64][40];  // 64 rows x 32 k, pad to 40 shorts (80B rows, 16B-aligned)
  __shared__ short Bs[64][40];

  const int t = threadIdx.x;
  const int lane = t & 63, wave = t >> 6;
  const int wr = wave >> 1, wc = wave & 1;
  const int l15 = lane & 15, l4 = lane >> 4;
  const int bm = blockIdx.x, bn = blockIdx.y;

  f4 acc[2][2];
#pragma unroll
  for (int i = 0; i < 2; ++i)
#pragma unroll
    for (int j = 0; j < 2; ++j) acc[i][j] = (f4){0.f, 0.f, 0.f, 0.f};

  const int sr = t >> 2, sc = (t & 3) * 8;
  const float* xrow = X + (size_t)(bm * 64 + sr) * NB + sc;
  const float* wrow = Wt + (size_t)(bn * 64 + sr) * NB + sc;

  for (int k0 = 0; k0 < NB; k0 += 32) {
    f4 a0 = *(const f4*)(xrow + k0);
    f4 a1 = *(const f4*)(xrow + k0 + 4);
    f4 b0 = *(const f4*)(wrow + k0);
    f4 b1 = *(const f4*)(wrow + k0 + 4);
    bf8 av, bv;
#pragma unroll
    for (int j = 0; j < 4; ++j) {
      av[j] = f2bf(a0[j]); av[4 + j] = f2bf(a1[j]);
      bv[j] = f2bf(b0[j]); bv[4 + j] = f2bf(b1[j]);
    }
    __syncthreads();
    *(bf8*)&As[sr][sc] = av;
    *(bf8*)&Bs[sr][sc] = bv;
    __syncthreads();
    bf8 af[2], bg[2];
    af[0] = *(bf8*)&As[wr * 32 + l15][l4 * 8];
    af[1] = *(bf8*)&As[wr * 32 + 16 + l15][l4 * 8];
    bg[0] = *(bf8*)&Bs[wc * 32 + l15][l4 * 8];
    bg[1] = *(bf8*)&Bs[wc * 32 + 16 + l15][l4 * 8];
#pragma unroll
    for (int mt = 0; mt < 2; ++mt)
#pragma unroll
      for (int nt = 0; nt < 2; ++nt)
        acc[mt][nt] = mfma16(af[mt], bg[nt], acc[mt][nt]);
  }
#pragma unroll
  for (int mt = 0; mt < 2; ++mt)
#pragma unroll
    for (int nt = 0; nt < 2; ++nt)
#pragma unroll
      for (int r = 0; r < 4; ++r) {
        int row = bm * 64 + wr * 32 + mt * 16 + l4 * 4 + r;
        int col = bn * 64 + wc * 32 + nt * 16 + l15;
        Out[(size_t)row * NB + col] = f2bf(acc[mt][nt][r] + Bb[col]);
      }
}

// ---------------- depthwise conv (q,k): writes [b,h,w,d] bf16 ----------------
__global__ __launch_bounds__(256) void dwconv_qk(
    const short* __restrict__ q0, const short* __restrict__ k0,
    const float* __restrict__ qcw, const float* __restrict__ qcb,
    const float* __restrict__ kcw, const float* __restrict__ kcb,
    short* __restrict__ qb, short* __restrict__ kb)
{
  const int p = blockIdx.y;
  const short* src = p ? k0 : q0;
  const float* cw = p ? kcw : qcw;
  const float* cb = p ? kcb : qcb;
  short* dst = p ? kb : qb;

  int idx = blockIdx.x * 256 + threadIdx.x;  // over 4096*512
  if (idx >= MTOT * NB) return;
  int c = idx & (NB - 1);
  int m = idx >> 9;
  int w = m & (CROP - 1);
  int b = m >> 10;
  float acc = cb[c] + cw[c * 3 + 1] * bf2f(src[idx]);
  if (w > 0) acc += cw[c * 3 + 0] * bf2f(src[idx - NB]);
  if (w < CROP - 1) acc += cw[c * 3 + 2] * bf2f(src[idx + NB]);
  int h = c >> 6, d = c & 63;
  dst[((size_t)(b * NH + h) * CROP + w) * HD + d] = f2bf(acc);
}

// ---------------- depthwise conv (v): writes transposed [b*512 + c][w] bf16 ----------------
__global__ __launch_bounds__(256) void dwconv_v(
    const short* __restrict__ v0, const float* __restrict__ vcw,
    const float* __restrict__ vcb, short* __restrict__ vb)
{
  __shared__ short T[64][72];  // [c_local][w_local], 144B rows (16B-aligned)
  const int w0 = blockIdx.x * 64, c0 = blockIdx.y * 64, b = blockIdx.z;
  const int t = threadIdx.x;
  const int cl = t & 63;
  const int wq = t >> 6;  // 0..3, 16 w each
  const int c = c0 + cl;
  const float kk0 = vcw[c * 3 + 0], kk1 = vcw[c * 3 + 1], kk2 = vcw[c * 3 + 2];
  const float bias = vcb[c];
#pragma unroll
  for (int ww = 0; ww < 16; ++ww) {
    int w = w0 + wq * 16 + ww;
    size_t m = (size_t)b * CROP + w;
    float acc = bias + kk1 * bf2f(v0[m * NB + c]);
    if (w > 0) acc += kk0 * bf2f(v0[(m - 1) * NB + c]);
    if (w < CROP - 1) acc += kk2 * bf2f(v0[(m + 1) * NB + c]);
    T[cl][wq * 16 + ww] = f2bf(acc);
  }
  __syncthreads();
  const int orow = t >> 2;          // c_local
  const int ocol = (t & 3) * 16;    // w_local chunk
  short* dst = vb + ((size_t)(b * NB) + c0 + orow) * CROP + w0 + ocol;
  *(bf8*)(dst) = *(bf8*)&T[orow][ocol];
  *(bf8*)(dst + 8) = *(bf8*)&T[orow][ocol + 8];
}

// ---------------- flash attention with relative-position term ----------------
__global__ __launch_bounds__(256) void attn_kernel(
    const short* __restrict__ Qb, const short* __restrict__ Kb,
    const short* __restrict__ Vb, const short* __restrict__ ErT,
    short* __restrict__ Ao)
{
  __shared__ short Ks[64][72];
  __shared__ short Qs[64][72];
  __shared__ short Vs[64][72];       // [d][j] (pre-transposed V)
  __shared__ short Ps[4][16][72];    // per-wave P tile [16 rows][64 j]

  const int qt = blockIdx.x, h = blockIdx.y, b = blockIdx.z;
  const int bh = b * NH + h;
  const int t = threadIdx.x;
  const int lane = t & 63, wave = t >> 6;
  const int l15 = lane & 15, l4 = lane >> 4;
  const int wq = qt * 64 + wave * 16;  // this wave's 16 Q rows

  // A-fragments of Q_I and erT_I, resident for the whole J loop
  bf8 qa[2], ea[2];
  {
    const short* qrow = Qb + ((size_t)bh * CROP + wq + l15) * HD + l4 * 8;
    qa[0] = *(const bf8*)(qrow);
    qa[1] = *(const bf8*)(qrow + 32);
    const short* erow = ErT + (size_t)(wq + l15) * HD + l4 * 8;
    ea[0] = *(const bf8*)(erow);
    ea[1] = *(const bf8*)(erow + 32);
  }

  float mr[4], lr[4];
  f4 oacc[4];
#pragma unroll
  for (int r = 0; r < 4; ++r) { mr[r] = -1e30f; lr[r] = 0.f; }
#pragma unroll
  for (int nt = 0; nt < 4; ++nt) oacc[nt] = (f4){0.f, 0.f, 0.f, 0.f};

  const int sr = t >> 2, sc = (t & 3) * 16;
  const short* ksrc = Kb + ((size_t)bh * CROP + sr) * HD + sc;
  const short* qsrc = Qb + ((size_t)bh * CROP + sr) * HD + sc;
  const short* vsrc = Vb + ((size_t)bh * HD + sr) * CROP + sc;

  const float isc = 0.044194173824159216f;  // 1/sqrt(512)

  for (int j0 = 0; j0 < CROP; j0 += 64) {
    __syncthreads();
    *(bf8*)&Ks[sr][sc]     = *(const bf8*)(ksrc + j0 * HD);
    *(bf8*)&Ks[sr][sc + 8] = *(const bf8*)(ksrc + j0 * HD + 8);
    *(bf8*)&Qs[sr][sc]     = *(const bf8*)(qsrc + j0 * HD);
    *(bf8*)&Qs[sr][sc + 8] = *(const bf8*)(qsrc + j0 * HD + 8);
    *(bf8*)&Vs[sr][sc]     = *(const bf8*)(vsrc + j0);
    *(bf8*)&Vs[sr][sc + 8] = *(const bf8*)(vsrc + j0 + 8);
    __syncthreads();

    // S tile [16 rows][64 j] = Q_I K_J^T + erT_I Q_J^T
    f4 sacc[4];
#pragma unroll
    for (int nt = 0; nt < 4; ++nt) sacc[nt] = (f4){0.f, 0.f, 0.f, 0.f};
#pragma unroll
    for (int ks = 0; ks < 2; ++ks) {
#pragma unroll
      for (int nt = 0; nt < 4; ++nt) {
        bf8 kf = *(bf8*)&Ks[nt * 16 + l15][ks * 32 + l4 * 8];
        sacc[nt] = mfma16(qa[ks], kf, sacc[nt]);
        bf8 qf = *(bf8*)&Qs[nt * 16 + l15][ks * 32 + l4 * 8];
        sacc[nt] = mfma16(ea[ks], qf, sacc[nt]);
      }
    }

    // online softmax; lanes with same l4 hold row (l4*4+r) across 16 columns
#pragma unroll
    for (int r = 0; r < 4; ++r) {
      float rowmax = fmaxf(fmaxf(sacc[0][r], sacc[1][r]),
                           fmaxf(sacc[2][r], sacc[3][r])) * isc;
#pragma unroll
      for (int off = 1; off < 16; off <<= 1)
        rowmax = fmaxf(rowmax, __shfl_xor(rowmax, off));
      float mnew = fmaxf(mr[r], rowmax);
      float alpha = __expf(mr[r] - mnew);
      float rs = 0.f;
      float pv[4];
#pragma unroll
      for (int nt = 0; nt < 4; ++nt) {
        pv[nt] = __expf(sacc[nt][r] * isc - mnew);
        rs += pv[nt];
      }
#pragma unroll
      for (int off = 1; off < 16; off <<= 1) rs += __shfl_xor(rs, off);
      lr[r] = lr[r] * alpha + rs;
      mr[r] = mnew;
#pragma unroll
      for (int nt = 0; nt < 4; ++nt) oacc[nt][r] *= alpha;
      const int prow = l4 * 4 + r;
#pragma unroll
      for (int nt = 0; nt < 4; ++nt)
        Ps[wave][prow][nt * 16 + l15] = f2bf(pv[nt]);
    }

    // O += P @ V_J  (A = P rows, B = Vs[d][j] read as B[j][d])
#pragma unroll
    for (int ks = 0; ks < 2; ++ks) {
      bf8 pf = *(bf8*)&Ps[wave][l15][ks * 32 + l4 * 8];
#pragma unroll
      for (int nt = 0; nt < 4; ++nt) {
        bf8 vf = *(bf8*)&Vs[nt * 16 + l15][ks * 32 + l4 * 8];
        oacc[nt] = mfma16(pf, vf, oacc[nt]);
      }
    }
  }

#pragma unroll
  for (int r = 0; r < 4; ++r) {
    float inv = 1.f / lr[r];
    const int row = b * CROP + qt * 64 + wave * 16 + l4 * 4 + r;
#pragma unroll
    for (int nt = 0; nt < 4; ++nt) {
      const int col = h * HD + nt * 16 + l15;
      Ao[(size_t)row * NB + col] = f2bf(oacc[nt][r] * inv);
    }
  }
}

// ---------------- output GEMM: Out[m,n] = sum_k A[m,k]*W[n,k] + b[n] (fp32 out) ----------------
__global__ __launch_bounds__(256) void out_gemm(
    const short* __restrict__ A, const float* __restrict__ Wt,
    const float* __restrict__ Bb, float* __restrict__ Out)
{
  __shared__ short As[64][40];
  __shared__ short Bs[64][40];
  const int t = threadIdx.x;
  const int lane = t & 63, wave = t >> 6;
  const int wr = wave >> 1, wc = wave & 1;
  const int l15 = lane & 15, l4 = lane >> 4;
  const int bm = blockIdx.x, bn = blockIdx.y;

  f4 acc[2][2];
#pragma unroll
  for (int i = 0; i < 2; ++i)
#pragma unroll
    for (int j = 0; j < 2; ++j) acc[i][j] = (f4){0.f, 0.f, 0.f, 0.f};

  const int sr = t >> 2, sc = (t & 3) * 8;
  const short* arow = A + (size_t)(bm * 64 + sr) * NB + sc;
  const float* wrow = Wt + (size_t)(bn * 64 + sr) * NB + sc;

  for (int k0 = 0; k0 < NB; k0 += 32) {
    bf8 av = *(const bf8*)(arow + k0);
    f4 b0 = *(const f4*)(wrow + k0);
    f4 b1 = *(const f4*)(wrow + k0 + 4);
    bf8 bv;
#pragma unroll
    for (int j = 0; j < 4; ++j) { bv[j] = f2bf(b0[j]); bv[4 + j] = f2bf(b1[j]); }
    __syncthreads();
    *(bf8*)&As[sr][sc] = av;
    *(bf8*)&Bs[sr][sc] = bv;
    __syncthreads();
    bf8 af[2], bg[2];
    af[0] = *(bf8*)&As[wr * 32 + l15][l4 * 8];
    af[1] = *(bf8*)&As[wr * 32 + 16 + l15][l4 * 8];
    bg[0] = *(bf8*)&Bs[wc * 32 + l15][l4 * 8];
    bg[1] = *(bf8*)&Bs[wc * 32 + 16 + l15][l4 * 8];
#pragma unroll
    for (int mt = 0; mt < 2; ++mt)
#pragma unroll
      for (int nt = 0; nt < 2; ++nt)
        acc[mt][nt] = mfma16(af[mt], bg[nt], acc[mt][nt]);
  }
#pragma unroll
  for (int mt = 0; mt < 2; ++mt)
#pragma unroll
    for (int nt = 0; nt < 2; ++nt)
#pragma unroll
      for (int r = 0; r < 4; ++r) {
        int row = bm * 64 + wr * 32 + mt * 16 + l4 * 4 + r;
        int col = bn * 64 + wc * 32 + nt * 16 + l15;
        Out[(size_t)row * NB + col] = acc[mt][nt][r] + Bb[col];
      }
}

extern "C" void kernel_launch(void* const* d_in, const int* in_sizes, int n_in,
                              void* d_out, int out_size, void* d_ws, size_t ws_size,
                              hipStream_t stream) {
  (void)in_sizes; (void)n_in; (void)out_size; (void)ws_size;
  const float* x    = (const float*)d_in[0];
  const float* q_w  = (const float*)d_in[1];
  const float* q_b  = (const float*)d_in[2];
  const float* q_cw = (const float*)d_in[3];
  const float* q_cb = (const float*)d_in[4];
  const float* k_w  = (const float*)d_in[5];
  const float* k_b  = (const float*)d_in[6];
  const float* k_cw = (const float*)d_in[7];
  const float* k_cb = (const float*)d_in[8];
  const float* v_w  = (const float*)d_in[9];
  const float* v_b  = (const float*)d_in[10];
  const float* v_cw = (const float*)d_in[11];
  const float* v_cb = (const float*)d_in[12];
  const float* o_w  = (const float*)d_in[13];
  const float* o_b  = (const float*)d_in[14];
  const float* er   = (const float*)d_in[15];
  float* out = (float*)d_out;

  char* ws = (char*)d_ws;
  const size_t SZ = (size_t)MTOT * NB * 2;  // 4 MiB per bf16 [4096,512] buffer
  short* q0  = (short*)(ws + 0 * SZ);
  short* k0  = (short*)(ws + 1 * SZ);
  short* v0  = (short*)(ws + 2 * SZ);
  short* qb2 = (short*)(ws + 3 * SZ);
  short* kb2 = (short*)(ws + 4 * SZ);
  short* vb2 = (short*)(ws + 5 * SZ);
  short* ao  = (short*)(ws + 6 * SZ);
  short* erT = (short*)(ws + 7 * SZ);  // 128 KiB

  ert_kernel<<<dim3(256), dim3(256), 0, stream>>>(er, erT);
  proj_gemm<<<dim3(64, 8, 3), dim3(256), 0, stream>>>(
      x, q_w, q_b, k_w, k_b, v_w, v_b, q0, k0, v0);
  dwconv_qk<<<dim3(8192, 2), dim3(256), 0, stream>>>(
      q0, k0, q_cw, q_cb, k_cw, k_cb, qb2, kb2);
  dwconv_v<<<dim3(16, 8, 4), dim3(256), 0, stream>>>(v0, v_cw, v_cb, vb2);
  attn_kernel<<<dim3(16, 8, 4), dim3(256), 0, stream>>>(qb2, kb2, vb2, erT, ao);
  out_gemm<<<dim3(64, 8), dim3(256), 0, stream>>>(ao, o_w, o_b, out);
}

// Round 2
// 105.054 us; speedup vs baseline: 1.1640x; 1.1640x over previous
//
#include <hip/hip_runtime.h>
#include <hip/hip_bf16.h>
#include <math.h>

// MultibandFrameAttention: B=4, W=1024, C=512, H=8, D=64
// R2: bf16 pre-convert for GEMMs (BK=64, no cvt in hot loop);
//     flash attention split-j x2 (occupancy 20%->~50%) + combine kernel;
//     s_setprio around attn MFMA clusters.

#define CROP 1024
#define NB 512
#define NH 8
#define HD 64
#define NBATCH 4
#define MTOT 4096
#define NBH 32          // NBATCH*NH
#define JSPLIT 2
#define ROWS_TOT 32768  // NBH*CROP

typedef __attribute__((ext_vector_type(8))) short bf8;
typedef __attribute__((ext_vector_type(4))) float f4;
typedef __attribute__((ext_vector_type(8))) _Float16 h8;

__device__ __forceinline__ short f2bf(float f) {
  union { float f; unsigned u; } v; v.f = f;
  unsigned r = (v.u + 0x7fffu + ((v.u >> 16) & 1u)) >> 16;
  return (short)r;
}
__device__ __forceinline__ float bf2f(short s) {
  union { unsigned u; float f; } v; v.u = ((unsigned)(unsigned short)s) << 16;
  return v.f;
}
__device__ __forceinline__ f4 mfma16(bf8 a, bf8 b, f4 c) {
  return __builtin_amdgcn_mfma_f32_16x16x32_bf16(a, b, c, 0, 0, 0);
}

// ---------------- fp32 -> bf16 converts ----------------
__global__ void cvt_x_kernel(const float* __restrict__ src, short* __restrict__ dst) {
  int i = (blockIdx.x * 256 + threadIdx.x) * 8;  // n = 4096*512
  f4 a = *(const f4*)(src + i);
  f4 b = *(const f4*)(src + i + 4);
  bf8 o;
#pragma unroll
  for (int j = 0; j < 4; ++j) { o[j] = f2bf(a[j]); o[4 + j] = f2bf(b[j]); }
  *(bf8*)(dst + i) = o;
}

__global__ void cvt_w_kernel(const float* __restrict__ w0, const float* __restrict__ w1,
                             const float* __restrict__ w2, const float* __restrict__ w3,
                             short* __restrict__ wb) {
  int p = blockIdx.y;
  const float* s = (p == 0) ? w0 : (p == 1) ? w1 : (p == 2) ? w2 : w3;
  int i = (blockIdx.x * 256 + threadIdx.x) * 8;  // n = 512*512
  f4 a = *(const f4*)(s + i);
  f4 b = *(const f4*)(s + i + 4);
  bf8 o;
#pragma unroll
  for (int j = 0; j < 4; ++j) { o[j] = f2bf(a[j]); o[4 + j] = f2bf(b[j]); }
  *(bf8*)(wb + (size_t)p * NB * NB + i) = o;
}

// ---------------- er transpose: erT[w][d] = bf16(er[d][w]) ----------------
__global__ void ert_kernel(const float* __restrict__ er, short* __restrict__ erT) {
  int idx = blockIdx.x * 256 + threadIdx.x;
  if (idx >= HD * CROP) return;
  int w = idx >> 6, d = idx & 63;
  erT[idx] = f2bf(er[d * CROP + w]);
}

// ---------------- QKV projection GEMM (bf16 in, BK=64) ----------------
__global__ __launch_bounds__(256) void proj_gemm2(
    const short* __restrict__ Xb, const short* __restrict__ Wb,
    const float* __restrict__ B0, const float* __restrict__ B1, const float* __restrict__ B2,
    short* __restrict__ O0, short* __restrict__ O1, short* __restrict__ O2)
{
  const int p = blockIdx.z;
  const short* Wt = Wb + (size_t)p * NB * NB;
  const float* Bb = (p == 0) ? B0 : (p == 1) ? B1 : B2;
  short* Out = (p == 0) ? O0 : (p == 1) ? O1 : O2;

  __shared__ short As[64][72];
  __shared__ short Bs[64][72];

  const int t = threadIdx.x;
  const int lane = t & 63, wave = t >> 6;
  const int wr = wave >> 1, wc = wave & 1;
  const int l15 = lane & 15, l4 = lane >> 4;
  const int bm = blockIdx.x, bn = blockIdx.y;

  f4 acc[2][2];
#pragma unroll
  for (int i = 0; i < 2; ++i)
#pragma unroll
    for (int j = 0; j < 2; ++j) acc[i][j] = (f4){0.f, 0.f, 0.f, 0.f};

  const int sr = t >> 2, sc = (t & 3) * 16;
  const short* xrow = Xb + (size_t)(bm * 64 + sr) * NB + sc;
  const short* wrow = Wt + (size_t)(bn * 64 + sr) * NB + sc;

  for (int k0 = 0; k0 < NB; k0 += 64) {
    bf8 a0 = *(const bf8*)(xrow + k0);
    bf8 a1 = *(const bf8*)(xrow + k0 + 8);
    bf8 b0 = *(const bf8*)(wrow + k0);
    bf8 b1 = *(const bf8*)(wrow + k0 + 8);
    __syncthreads();
    *(bf8*)&As[sr][sc] = a0;
    *(bf8*)&As[sr][sc + 8] = a1;
    *(bf8*)&Bs[sr][sc] = b0;
    *(bf8*)&Bs[sr][sc + 8] = b1;
    __syncthreads();
#pragma unroll
    for (int ks = 0; ks < 2; ++ks) {
      bf8 af[2], bg[2];
#pragma unroll
      for (int mt = 0; mt < 2; ++mt)
        af[mt] = *(bf8*)&As[wr * 32 + mt * 16 + l15][ks * 32 + l4 * 8];
#pragma unroll
      for (int nt = 0; nt < 2; ++nt)
        bg[nt] = *(bf8*)&Bs[wc * 32 + nt * 16 + l15][ks * 32 + l4 * 8];
#pragma unroll
      for (int mt = 0; mt < 2; ++mt)
#pragma unroll
        for (int nt = 0; nt < 2; ++nt)
          acc[mt][nt] = mfma16(af[mt], bg[nt], acc[mt][nt]);
    }
  }
#pragma unroll
  for (int mt = 0; mt < 2; ++mt)
#pragma unroll
    for (int nt = 0; nt < 2; ++nt)
#pragma unroll
      for (int r = 0; r < 4; ++r) {
        int row = bm * 64 + wr * 32 + mt * 16 + l4 * 4 + r;
        int col = bn * 64 + wc * 32 + nt * 16 + l15;
        Out[(size_t)row * NB + col] = f2bf(acc[mt][nt][r] + Bb[col]);
      }
}

// ---------------- depthwise conv (q,k): writes [b,h,w,d] bf16 ----------------
__global__ __launch_bounds__(256) void dwconv_qk(
    const short* __restrict__ q0, const short* __restrict__ k0,
    const float* __restrict__ qcw, const float* __restrict__ qcb,
    const float* __restrict__ kcw, const float* __restrict__ kcb,
    short* __restrict__ qb, short* __restrict__ kb)
{
  const int p = blockIdx.y;
  const short* src = p ? k0 : q0;
  const float* cw = p ? kcw : qcw;
  const float* cb = p ? kcb : qcb;
  short* dst = p ? kb : qb;

  int idx = blockIdx.x * 256 + threadIdx.x;
  if (idx >= MTOT * NB) return;
  int c = idx & (NB - 1);
  int m = idx >> 9;
  int w = m & (CROP - 1);
  int b = m >> 10;
  float acc = cb[c] + cw[c * 3 + 1] * bf2f(src[idx]);
  if (w > 0) acc += cw[c * 3 + 0] * bf2f(src[idx - NB]);
  if (w < CROP - 1) acc += cw[c * 3 + 2] * bf2f(src[idx + NB]);
  int h = c >> 6, d = c & 63;
  dst[((size_t)(b * NH + h) * CROP + w) * HD + d] = f2bf(acc);
}

// ---------------- depthwise conv (v): writes transposed [b*512 + c][w] bf16 ----------------
__global__ __launch_bounds__(256) void dwconv_v(
    const short* __restrict__ v0, const float* __restrict__ vcw,
    const float* __restrict__ vcb, short* __restrict__ vb)
{
  __shared__ short T[64][72];
  const int w0 = blockIdx.x * 64, c0 = blockIdx.y * 64, b = blockIdx.z;
  const int t = threadIdx.x;
  const int cl = t & 63;
  const int wq = t >> 6;
  const int c = c0 + cl;
  const float kk0 = vcw[c * 3 + 0], kk1 = vcw[c * 3 + 1], kk2 = vcw[c * 3 + 2];
  const float bias = vcb[c];
#pragma unroll
  for (int ww = 0; ww < 16; ++ww) {
    int w = w0 + wq * 16 + ww;
    size_t m = (size_t)b * CROP + w;
    float acc = bias + kk1 * bf2f(v0[m * NB + c]);
    if (w > 0) acc += kk0 * bf2f(v0[(m - 1) * NB + c]);
    if (w < CROP - 1) acc += kk2 * bf2f(v0[(m + 1) * NB + c]);
    T[cl][wq * 16 + ww] = f2bf(acc);
  }
  __syncthreads();
  const int orow = t >> 2;
  const int ocol = (t & 3) * 16;
  short* dst = vb + ((size_t)(b * NB) + c0 + orow) * CROP + w0 + ocol;
  *(bf8*)(dst) = *(bf8*)&T[orow][ocol];
  *(bf8*)(dst + 8) = *(bf8*)&T[orow][ocol + 8];
}

// ---------------- flash attention partial (split-j) ----------------
// blockIdx: x = qt (16), y = bh (32), z = s (JSPLIT)
// Writes unnormalized O (fp16) + m,l per row.
__global__ __launch_bounds__(256) void attn_part(
    const short* __restrict__ Qb, const short* __restrict__ Kb,
    const short* __restrict__ Vb, const short* __restrict__ ErT,
    _Float16* __restrict__ Op, float* __restrict__ mbuf, float* __restrict__ lbuf)
{
  __shared__ short Ks[64][72];
  __shared__ short Qs[64][72];
  __shared__ short Vs[64][72];
  __shared__ short Ps[4][16][72];

  const int qt = blockIdx.x, bh = blockIdx.y, s = blockIdx.z;
  const int t = threadIdx.x;
  const int lane = t & 63, wave = t >> 6;
  const int l15 = lane & 15, l4 = lane >> 4;
  const int wq = qt * 64 + wave * 16;

  bf8 qa[2], ea[2];
  {
    const short* qrow = Qb + ((size_t)bh * CROP + wq + l15) * HD + l4 * 8;
    qa[0] = *(const bf8*)(qrow);
    qa[1] = *(const bf8*)(qrow + 32);
    const short* erow = ErT + (size_t)(wq + l15) * HD + l4 * 8;
    ea[0] = *(const bf8*)(erow);
    ea[1] = *(const bf8*)(erow + 32);
  }

  float mr[4], lr[4];
  f4 oacc[4];
#pragma unroll
  for (int r = 0; r < 4; ++r) { mr[r] = -1e30f; lr[r] = 0.f; }
#pragma unroll
  for (int nt = 0; nt < 4; ++nt) oacc[nt] = (f4){0.f, 0.f, 0.f, 0.f};

  const int sr = t >> 2, sc = (t & 3) * 16;
  const short* ksrc = Kb + ((size_t)bh * CROP + sr) * HD + sc;
  const short* qsrc = Qb + ((size_t)bh * CROP + sr) * HD + sc;
  const short* vsrc = Vb + ((size_t)bh * HD + sr) * CROP + sc;

  const float isc = 0.044194173824159216f;  // 1/sqrt(512)
  const int jbase = s * (CROP / JSPLIT);

  for (int jj = 0; jj < CROP / JSPLIT; jj += 64) {
    const int j0 = jbase + jj;
    __syncthreads();
    *(bf8*)&Ks[sr][sc]     = *(const bf8*)(ksrc + j0 * HD);
    *(bf8*)&Ks[sr][sc + 8] = *(const bf8*)(ksrc + j0 * HD + 8);
    *(bf8*)&Qs[sr][sc]     = *(const bf8*)(qsrc + j0 * HD);
    *(bf8*)&Qs[sr][sc + 8] = *(const bf8*)(qsrc + j0 * HD + 8);
    *(bf8*)&Vs[sr][sc]     = *(const bf8*)(vsrc + j0);
    *(bf8*)&Vs[sr][sc + 8] = *(const bf8*)(vsrc + j0 + 8);
    __syncthreads();

    f4 sacc[4];
#pragma unroll
    for (int nt = 0; nt < 4; ++nt) sacc[nt] = (f4){0.f, 0.f, 0.f, 0.f};
    __builtin_amdgcn_s_setprio(1);
#pragma unroll
    for (int ks = 0; ks < 2; ++ks) {
#pragma unroll
      for (int nt = 0; nt < 4; ++nt) {
        bf8 kf = *(bf8*)&Ks[nt * 16 + l15][ks * 32 + l4 * 8];
        sacc[nt] = mfma16(qa[ks], kf, sacc[nt]);
        bf8 qf = *(bf8*)&Qs[nt * 16 + l15][ks * 32 + l4 * 8];
        sacc[nt] = mfma16(ea[ks], qf, sacc[nt]);
      }
    }
    __builtin_amdgcn_s_setprio(0);

#pragma unroll
    for (int r = 0; r < 4; ++r) {
      float rowmax = fmaxf(fmaxf(sacc[0][r], sacc[1][r]),
                           fmaxf(sacc[2][r], sacc[3][r])) * isc;
#pragma unroll
      for (int off = 1; off < 16; off <<= 1)
        rowmax = fmaxf(rowmax, __shfl_xor(rowmax, off));
      float mnew = fmaxf(mr[r], rowmax);
      float alpha = __expf(mr[r] - mnew);
      float rs = 0.f;
      float pv[4];
#pragma unroll
      for (int nt = 0; nt < 4; ++nt) {
        pv[nt] = __expf(sacc[nt][r] * isc - mnew);
        rs += pv[nt];
      }
#pragma unroll
      for (int off = 1; off < 16; off <<= 1) rs += __shfl_xor(rs, off);
      lr[r] = lr[r] * alpha + rs;
      mr[r] = mnew;
#pragma unroll
      for (int nt = 0; nt < 4; ++nt) oacc[nt][r] *= alpha;
      const int prow = l4 * 4 + r;
#pragma unroll
      for (int nt = 0; nt < 4; ++nt)
        Ps[wave][prow][nt * 16 + l15] = f2bf(pv[nt]);
    }

    __builtin_amdgcn_s_setprio(1);
#pragma unroll
    for (int ks = 0; ks < 2; ++ks) {
      bf8 pf = *(bf8*)&Ps[wave][l15][ks * 32 + l4 * 8];
#pragma unroll
      for (int nt = 0; nt < 4; ++nt) {
        bf8 vf = *(bf8*)&Vs[nt * 16 + l15][ks * 32 + l4 * 8];
        oacc[nt] = mfma16(pf, vf, oacc[nt]);
      }
    }
    __builtin_amdgcn_s_setprio(0);
  }

  // store partials (unnormalized O in fp16, plus m,l)
#pragma unroll
  for (int r = 0; r < 4; ++r) {
    const int row = qt * 64 + wave * 16 + l4 * 4 + r;
    const size_t ridx = (size_t)(s * NBH + bh) * CROP + row;
#pragma unroll
    for (int nt = 0; nt < 4; ++nt)
      Op[ridx * HD + nt * 16 + l15] = (_Float16)oacc[nt][r];
    if (l15 == 0) { mbuf[ridx] = mr[r]; lbuf[ridx] = lr[r]; }
  }
}

// ---------------- combine partials -> ao [b*1024+w][512] bf16 ----------------
__global__ __launch_bounds__(256) void attn_combine(
    const _Float16* __restrict__ Op, const float* __restrict__ mbuf,
    const float* __restrict__ lbuf, short* __restrict__ Ao)
{
  const int t = threadIdx.x;
  const int idx = blockIdx.x * 32 + (t >> 3);   // (bh,row) index, 0..32767
  const int dth = (t & 7) * 8;
  float m0 = mbuf[idx], m1 = mbuf[ROWS_TOT + idx];
  float l0 = lbuf[idx], l1 = lbuf[ROWS_TOT + idx];
  float m = fmaxf(m0, m1);
  float a0 = __expf(m0 - m), a1 = __expf(m1 - m);
  float inv = 1.f / (l0 * a0 + l1 * a1);
  a0 *= inv; a1 *= inv;
  h8 v0 = *(const h8*)(Op + (size_t)idx * HD + dth);
  h8 v1 = *(const h8*)(Op + ((size_t)ROWS_TOT + idx) * HD + dth);
  const int bh = idx >> 10, row = idx & (CROP - 1);
  const int b = bh >> 3, h = bh & 7;
  short* dst = Ao + ((size_t)(b * CROP + row)) * NB + h * HD + dth;
  bf8 o;
#pragma unroll
  for (int j = 0; j < 8; ++j)
    o[j] = f2bf((float)v0[j] * a0 + (float)v1[j] * a1);
  *(bf8*)dst = o;
}

// ---------------- output GEMM (bf16 in, fp32 out, BK=64) ----------------
__global__ __launch_bounds__(256) void out_gemm2(
    const short* __restrict__ A, const short* __restrict__ Wt,
    const float* __restrict__ Bb, float* __restrict__ Out)
{
  __shared__ short As[64][72];
  __shared__ short Bs[64][72];
  const int t = threadIdx.x;
  const int lane = t & 63, wave = t >> 6;
  const int wr = wave >> 1, wc = wave & 1;
  const int l15 = lane & 15, l4 = lane >> 4;
  const int bm = blockIdx.x, bn = blockIdx.y;

  f4 acc[2][2];
#pragma unroll
  for (int i = 0; i < 2; ++i)
#pragma unroll
    for (int j = 0; j < 2; ++j) acc[i][j] = (f4){0.f, 0.f, 0.f, 0.f};

  const int sr = t >> 2, sc = (t & 3) * 16;
  const short* arow = A + (size_t)(bm * 64 + sr) * NB + sc;
  const short* wrow = Wt + (size_t)(bn * 64 + sr) * NB + sc;

  for (int k0 = 0; k0 < NB; k0 += 64) {
    bf8 a0 = *(const bf8*)(arow + k0);
    bf8 a1 = *(const bf8*)(arow + k0 + 8);
    bf8 b0 = *(const bf8*)(wrow + k0);
    bf8 b1 = *(const bf8*)(wrow + k0 + 8);
    __syncthreads();
    *(bf8*)&As[sr][sc] = a0;
    *(bf8*)&As[sr][sc + 8] = a1;
    *(bf8*)&Bs[sr][sc] = b0;
    *(bf8*)&Bs[sr][sc + 8] = b1;
    __syncthreads();
#pragma unroll
    for (int ks = 0; ks < 2; ++ks) {
      bf8 af[2], bg[2];
#pragma unroll
      for (int mt = 0; mt < 2; ++mt)
        af[mt] = *(bf8*)&As[wr * 32 + mt * 16 + l15][ks * 32 + l4 * 8];
#pragma unroll
      for (int nt = 0; nt < 2; ++nt)
        bg[nt] = *(bf8*)&Bs[wc * 32 + nt * 16 + l15][ks * 32 + l4 * 8];
#pragma unroll
      for (int mt = 0; mt < 2; ++mt)
#pragma unroll
        for (int nt = 0; nt < 2; ++nt)
          acc[mt][nt] = mfma16(af[mt], bg[nt], acc[mt][nt]);
    }
  }
#pragma unroll
  for (int mt = 0; mt < 2; ++mt)
#pragma unroll
    for (int nt = 0; nt < 2; ++nt)
#pragma unroll
      for (int r = 0; r < 4; ++r) {
        int row = bm * 64 + wr * 32 + mt * 16 + l4 * 4 + r;
        int col = bn * 64 + wc * 32 + nt * 16 + l15;
        Out[(size_t)row * NB + col] = acc[mt][nt][r] + Bb[col];
      }
}

extern "C" void kernel_launch(void* const* d_in, const int* in_sizes, int n_in,
                              void* d_out, int out_size, void* d_ws, size_t ws_size,
                              hipStream_t stream) {
  (void)in_sizes; (void)n_in; (void)out_size; (void)ws_size;
  const float* x    = (const float*)d_in[0];
  const float* q_w  = (const float*)d_in[1];
  const float* q_b  = (const float*)d_in[2];
  const float* q_cw = (const float*)d_in[3];
  const float* q_cb = (const float*)d_in[4];
  const float* k_w  = (const float*)d_in[5];
  const float* k_b  = (const float*)d_in[6];
  const float* k_cw = (const float*)d_in[7];
  const float* k_cb = (const float*)d_in[8];
  const float* v_w  = (const float*)d_in[9];
  const float* v_b  = (const float*)d_in[10];
  const float* v_cw = (const float*)d_in[11];
  const float* v_cb = (const float*)d_in[12];
  const float* o_w  = (const float*)d_in[13];
  const float* o_b  = (const float*)d_in[14];
  const float* er   = (const float*)d_in[15];
  float* out = (float*)d_out;

  char* ws = (char*)d_ws;
  const size_t SZ = (size_t)MTOT * NB * 2;  // 4 MiB
  short* q0  = (short*)(ws + 0 * SZ);
  short* k0  = (short*)(ws + 1 * SZ);
  short* v0  = (short*)(ws + 2 * SZ);
  short* qb2 = (short*)(ws + 3 * SZ);
  short* kb2 = (short*)(ws + 4 * SZ);
  short* vb2 = (short*)(ws + 5 * SZ);
  short* ao  = (short*)(ws + 6 * SZ);
  short* erT = (short*)(ws + 7 * SZ);            // 128 KiB
  short* xb  = (short*)(ws + 7 * SZ + (512 << 10));  // 4 MiB
  short* wb  = (short*)(ws + 8 * SZ + (512 << 10));  // 4x512x512 bf16 = 2 MiB

  // attn partials alias dead q0/k0/v0:
  _Float16* Op = (_Float16*)(ws + 0 * SZ);       // [2][32][1024][64] fp16 = 8 MiB
  float* mbuf  = (float*)(ws + 2 * SZ);          // [2][32768] = 256 KiB
  float* lbuf  = (float*)(ws + 2 * SZ + (256 << 10));

  ert_kernel<<<dim3(256), dim3(256), 0, stream>>>(er, erT);
  cvt_x_kernel<<<dim3(1024), dim3(256), 0, stream>>>(x, xb);
  cvt_w_kernel<<<dim3(128, 4), dim3(256), 0, stream>>>(q_w, k_w, v_w, o_w, wb);
  proj_gemm2<<<dim3(64, 8, 3), dim3(256), 0, stream>>>(
      xb, wb, q_b, k_b, v_b, q0, k0, v0);
  dwconv_qk<<<dim3(8192, 2), dim3(256), 0, stream>>>(
      q0, k0, q_cw, q_cb, k_cw, k_cb, qb2, kb2);
  dwconv_v<<<dim3(16, 8, 4), dim3(256), 0, stream>>>(v0, v_cw, v_cb, vb2);
  attn_part<<<dim3(16, NBH, JSPLIT), dim3(256), 0, stream>>>(
      qb2, kb2, vb2, erT, Op, mbuf, lbuf);
  attn_combine<<<dim3(1024), dim3(256), 0, stream>>>(Op, mbuf, lbuf, ao);
  out_gemm2<<<dim3(64, 8), dim3(256), 0, stream>>>(
      ao, wb + 3 * NB * NB, o_b, out);
}

// Round 3
// 87.222 us; speedup vs baseline: 1.4019x; 1.2044x over previous
//
#include <hip/hip_runtime.h>
#include <hip/hip_bf16.h>
#include <math.h>

// MultibandFrameAttention: B=4, W=1024, C=512, H=8, D=64
// R3: no-max softmax (exact in fp32 at these magnitudes) -> serial chain cut;
//     isc folded into Q; 8-wave attn blocks (128 q-rows), JSPLIT=4;
//     dwconv_v rewritten LDS-staged + coalesced.

#define CROP 1024
#define NB 512
#define NH 8
#define HD 64
#define NBATCH 4
#define MTOT 4096
#define NBH 32
#define JSPLIT 4
#define ROWS_TOT 32768  // NBH*CROP

typedef __attribute__((ext_vector_type(8))) short bf8;
typedef __attribute__((ext_vector_type(4))) float f4;
typedef __attribute__((ext_vector_type(8))) _Float16 h8;

__device__ __forceinline__ short f2bf(float f) {
  union { float f; unsigned u; } v; v.f = f;
  unsigned r = (v.u + 0x7fffu + ((v.u >> 16) & 1u)) >> 16;
  return (short)r;
}
__device__ __forceinline__ float bf2f(short s) {
  union { unsigned u; float f; } v; v.u = ((unsigned)(unsigned short)s) << 16;
  return v.f;
}
__device__ __forceinline__ f4 mfma16(bf8 a, bf8 b, f4 c) {
  return __builtin_amdgcn_mfma_f32_16x16x32_bf16(a, b, c, 0, 0, 0);
}

#define ISC 0.044194173824159216f  // 1/sqrt(512)

// ---------------- fp32 -> bf16 converts ----------------
__global__ void cvt_x_kernel(const float* __restrict__ src, short* __restrict__ dst) {
  int i = (blockIdx.x * 256 + threadIdx.x) * 8;
  f4 a = *(const f4*)(src + i);
  f4 b = *(const f4*)(src + i + 4);
  bf8 o;
#pragma unroll
  for (int j = 0; j < 4; ++j) { o[j] = f2bf(a[j]); o[4 + j] = f2bf(b[j]); }
  *(bf8*)(dst + i) = o;
}

__global__ void cvt_w_kernel(const float* __restrict__ w0, const float* __restrict__ w1,
                             const float* __restrict__ w2, const float* __restrict__ w3,
                             short* __restrict__ wb) {
  int p = blockIdx.y;
  const float* s = (p == 0) ? w0 : (p == 1) ? w1 : (p == 2) ? w2 : w3;
  int i = (blockIdx.x * 256 + threadIdx.x) * 8;
  f4 a = *(const f4*)(s + i);
  f4 b = *(const f4*)(s + i + 4);
  bf8 o;
#pragma unroll
  for (int j = 0; j < 4; ++j) { o[j] = f2bf(a[j]); o[4 + j] = f2bf(b[j]); }
  *(bf8*)(wb + (size_t)p * NB * NB + i) = o;
}

// ---------------- er transpose: erT[w][d] = bf16(er[d][w]) (unscaled) ----------------
__global__ void ert_kernel(const float* __restrict__ er, short* __restrict__ erT) {
  int idx = blockIdx.x * 256 + threadIdx.x;
  if (idx >= HD * CROP) return;
  int w = idx >> 6, d = idx & 63;
  erT[idx] = f2bf(er[d * CROP + w]);
}

// ---------------- QKV projection GEMM (bf16 in, BK=64) ----------------
__global__ __launch_bounds__(256) void proj_gemm2(
    const short* __restrict__ Xb, const short* __restrict__ Wb,
    const float* __restrict__ B0, const float* __restrict__ B1, const float* __restrict__ B2,
    short* __restrict__ O0, short* __restrict__ O1, short* __restrict__ O2)
{
  const int p = blockIdx.z;
  const short* Wt = Wb + (size_t)p * NB * NB;
  const float* Bb = (p == 0) ? B0 : (p == 1) ? B1 : B2;
  short* Out = (p == 0) ? O0 : (p == 1) ? O1 : O2;

  __shared__ short As[64][72];
  __shared__ short Bs[64][72];

  const int t = threadIdx.x;
  const int lane = t & 63, wave = t >> 6;
  const int wr = wave >> 1, wc = wave & 1;
  const int l15 = lane & 15, l4 = lane >> 4;
  const int bm = blockIdx.x, bn = blockIdx.y;

  f4 acc[2][2];
#pragma unroll
  for (int i = 0; i < 2; ++i)
#pragma unroll
    for (int j = 0; j < 2; ++j) acc[i][j] = (f4){0.f, 0.f, 0.f, 0.f};

  const int sr = t >> 2, sc = (t & 3) * 16;
  const short* xrow = Xb + (size_t)(bm * 64 + sr) * NB + sc;
  const short* wrow = Wt + (size_t)(bn * 64 + sr) * NB + sc;

  for (int k0 = 0; k0 < NB; k0 += 64) {
    bf8 a0 = *(const bf8*)(xrow + k0);
    bf8 a1 = *(const bf8*)(xrow + k0 + 8);
    bf8 b0 = *(const bf8*)(wrow + k0);
    bf8 b1 = *(const bf8*)(wrow + k0 + 8);
    __syncthreads();
    *(bf8*)&As[sr][sc] = a0;
    *(bf8*)&As[sr][sc + 8] = a1;
    *(bf8*)&Bs[sr][sc] = b0;
    *(bf8*)&Bs[sr][sc + 8] = b1;
    __syncthreads();
#pragma unroll
    for (int ks = 0; ks < 2; ++ks) {
      bf8 af[2], bg[2];
#pragma unroll
      for (int mt = 0; mt < 2; ++mt)
        af[mt] = *(bf8*)&As[wr * 32 + mt * 16 + l15][ks * 32 + l4 * 8];
#pragma unroll
      for (int nt = 0; nt < 2; ++nt)
        bg[nt] = *(bf8*)&Bs[wc * 32 + nt * 16 + l15][ks * 32 + l4 * 8];
#pragma unroll
      for (int mt = 0; mt < 2; ++mt)
#pragma unroll
        for (int nt = 0; nt < 2; ++nt)
          acc[mt][nt] = mfma16(af[mt], bg[nt], acc[mt][nt]);
    }
  }
#pragma unroll
  for (int mt = 0; mt < 2; ++mt)
#pragma unroll
    for (int nt = 0; nt < 2; ++nt)
#pragma unroll
      for (int r = 0; r < 4; ++r) {
        int row = bm * 64 + wr * 32 + mt * 16 + l4 * 4 + r;
        int col = bn * 64 + wc * 32 + nt * 16 + l15;
        Out[(size_t)row * NB + col] = f2bf(acc[mt][nt][r] + Bb[col]);
      }
}

// ---------------- depthwise conv (q,k): writes [b,h,w,d] bf16; q scaled by ISC ----------------
__global__ __launch_bounds__(256) void dwconv_qk(
    const short* __restrict__ q0, const short* __restrict__ k0,
    const float* __restrict__ qcw, const float* __restrict__ qcb,
    const float* __restrict__ kcw, const float* __restrict__ kcb,
    short* __restrict__ qb, short* __restrict__ kb)
{
  const int p = blockIdx.y;
  const short* src = p ? k0 : q0;
  const float* cw = p ? kcw : qcw;
  const float* cb = p ? kcb : qcb;
  short* dst = p ? kb : qb;
  const float scale = p ? 1.0f : ISC;

  int idx = blockIdx.x * 256 + threadIdx.x;
  if (idx >= MTOT * NB) return;
  int c = idx & (NB - 1);
  int m = idx >> 9;
  int w = m & (CROP - 1);
  int b = m >> 10;
  float acc = cb[c] + cw[c * 3 + 1] * bf2f(src[idx]);
  if (w > 0) acc += cw[c * 3 + 0] * bf2f(src[idx - NB]);
  if (w < CROP - 1) acc += cw[c * 3 + 2] * bf2f(src[idx + NB]);
  int h = c >> 6, d = c & 63;
  dst[((size_t)(b * NH + h) * CROP + w) * HD + d] = f2bf(acc * scale);
}

// ---------------- depthwise conv (v): LDS-staged, writes transposed [b*512+c][w] ----------------
__global__ __launch_bounds__(256) void dwconv_v(
    const short* __restrict__ v0, const float* __restrict__ vcw,
    const float* __restrict__ vcb, short* __restrict__ vb)
{
  __shared__ short S[66][72];  // rows: w0-1 .. w0+64
  const int w0 = blockIdx.x * 64, c0 = blockIdx.y * 64, b = blockIdx.z;
  const int t = threadIdx.x;

#pragma unroll
  for (int i = 0; i < 3; ++i) {
    int r = i * 32 + (t >> 3);
    if (r < 66) {
      int w = w0 - 1 + r;
      int cg = (t & 7) * 8;
      bf8 val = (bf8){0, 0, 0, 0, 0, 0, 0, 0};
      if (w >= 0 && w < CROP)
        val = *(const bf8*)(v0 + ((size_t)b * CROP + w) * NB + c0 + cg);
      *(bf8*)&S[r][cg] = val;
    }
  }
  __syncthreads();

  const int c = t & 63, wv = t >> 6;
  const float k0 = vcw[(c0 + c) * 3 + 0];
  const float k1 = vcw[(c0 + c) * 3 + 1];
  const float k2 = vcw[(c0 + c) * 3 + 2];
  const float bias = vcb[c0 + c];

  float xa = bf2f(S[wv * 16][c]);
  float xb = bf2f(S[wv * 16 + 1][c]);
  short res[16];
#pragma unroll
  for (int ww = 0; ww < 16; ++ww) {
    float xc = bf2f(S[wv * 16 + ww + 2][c]);
    res[ww] = f2bf(bias + k0 * xa + k1 * xb + k2 * xc);
    xa = xb; xb = xc;
  }
  short* dst = vb + ((size_t)(b * NB) + c0 + c) * CROP + w0 + wv * 16;
  *(bf8*)dst = *(bf8*)&res[0];
  *(bf8*)(dst + 8) = *(bf8*)&res[8];
}

// ---------------- flash attention partial (split-j, no-max softmax) ----------------
// blockIdx: x = qt (8 x 128 rows), y = bh (32), z = s (JSPLIT)
__global__ __launch_bounds__(512) void attn_part(
    const short* __restrict__ Qb, const short* __restrict__ Kb,
    const short* __restrict__ Vb, const short* __restrict__ ErT,
    _Float16* __restrict__ Op, float* __restrict__ lbuf)
{
  __shared__ short Ks[64][72];
  __shared__ short Qs[64][72];
  __shared__ short Vs[64][72];
  __shared__ short Ps[8][16][72];

  const int qt = blockIdx.x, bh = blockIdx.y, s = blockIdx.z;
  const int t = threadIdx.x;
  const int lane = t & 63, wave = t >> 6;
  const int l15 = lane & 15, l4 = lane >> 4;
  const int wq = qt * 128 + wave * 16;

  bf8 qa[2], ea[2];
  {
    const short* qrow = Qb + ((size_t)bh * CROP + wq + l15) * HD + l4 * 8;
    qa[0] = *(const bf8*)(qrow);
    qa[1] = *(const bf8*)(qrow + 32);
    const short* erow = ErT + (size_t)(wq + l15) * HD + l4 * 8;
    ea[0] = *(const bf8*)(erow);
    ea[1] = *(const bf8*)(erow + 32);
  }

  float lsum[4] = {0.f, 0.f, 0.f, 0.f};
  f4 oacc[4];
#pragma unroll
  for (int nt = 0; nt < 4; ++nt) oacc[nt] = (f4){0.f, 0.f, 0.f, 0.f};

  const int sr2 = t >> 3, sc2 = (t & 7) * 8;
  const short* ksrc = Kb + ((size_t)bh * CROP + sr2) * HD + sc2;
  const short* qsrc = Qb + ((size_t)bh * CROP + sr2) * HD + sc2;
  const short* vsrc = Vb + ((size_t)bh * HD + sr2) * CROP + sc2;

  const int jbase = s * (CROP / JSPLIT);

  for (int jj = 0; jj < CROP / JSPLIT; jj += 64) {
    const int j0 = jbase + jj;
    __syncthreads();
    *(bf8*)&Ks[sr2][sc2] = *(const bf8*)(ksrc + j0 * HD);
    *(bf8*)&Qs[sr2][sc2] = *(const bf8*)(qsrc + j0 * HD);
    *(bf8*)&Vs[sr2][sc2] = *(const bf8*)(vsrc + j0);
    __syncthreads();

    // S tile [16 rows][64 j] = (Q*isc)_I K_J^T + erT_I (Q*isc)_J^T
    f4 sacc[4];
#pragma unroll
    for (int nt = 0; nt < 4; ++nt) sacc[nt] = (f4){0.f, 0.f, 0.f, 0.f};
    __builtin_amdgcn_s_setprio(1);
#pragma unroll
    for (int ks = 0; ks < 2; ++ks) {
#pragma unroll
      for (int nt = 0; nt < 4; ++nt) {
        bf8 kf = *(bf8*)&Ks[nt * 16 + l15][ks * 32 + l4 * 8];
        sacc[nt] = mfma16(qa[ks], kf, sacc[nt]);
        bf8 qf = *(bf8*)&Qs[nt * 16 + l15][ks * 32 + l4 * 8];
        sacc[nt] = mfma16(ea[ks], qf, sacc[nt]);
      }
    }
    __builtin_amdgcn_s_setprio(0);

    // exp (no max subtraction), accumulate per-lane row sums, P -> LDS
#pragma unroll
    for (int r = 0; r < 4; ++r) {
      const int prow = l4 * 4 + r;
      float pv0 = __expf(sacc[0][r]);
      float pv1 = __expf(sacc[1][r]);
      float pv2 = __expf(sacc[2][r]);
      float pv3 = __expf(sacc[3][r]);
      lsum[r] += (pv0 + pv1) + (pv2 + pv3);
      Ps[wave][prow][0 * 16 + l15] = f2bf(pv0);
      Ps[wave][prow][1 * 16 + l15] = f2bf(pv1);
      Ps[wave][prow][2 * 16 + l15] = f2bf(pv2);
      Ps[wave][prow][3 * 16 + l15] = f2bf(pv3);
    }

    __builtin_amdgcn_s_setprio(1);
#pragma unroll
    for (int ks = 0; ks < 2; ++ks) {
      bf8 pf = *(bf8*)&Ps[wave][l15][ks * 32 + l4 * 8];
#pragma unroll
      for (int nt = 0; nt < 4; ++nt) {
        bf8 vf = *(bf8*)&Vs[nt * 16 + l15][ks * 32 + l4 * 8];
        oacc[nt] = mfma16(pf, vf, oacc[nt]);
      }
    }
    __builtin_amdgcn_s_setprio(0);
  }

  // reduce row sums across the 16 lanes sharing each row (xor keeps l4 group)
#pragma unroll
  for (int r = 0; r < 4; ++r) {
#pragma unroll
    for (int off = 1; off < 16; off <<= 1)
      lsum[r] += __shfl_xor(lsum[r], off);
  }

#pragma unroll
  for (int r = 0; r < 4; ++r) {
    const int row = wq + l4 * 4 + r;
    const size_t ridx = (size_t)(s * NBH + bh) * CROP + row;
#pragma unroll
    for (int nt = 0; nt < 4; ++nt)
      Op[ridx * HD + nt * 16 + l15] = (_Float16)oacc[nt][r];
    if (l15 == 0) lbuf[ridx] = lsum[r];
  }
}

// ---------------- combine partials -> ao [b*1024+w][512] bf16 ----------------
__global__ __launch_bounds__(256) void attn_combine(
    const _Float16* __restrict__ Op, const float* __restrict__ lbuf,
    short* __restrict__ Ao)
{
  const int t = threadIdx.x;
  const int idx = blockIdx.x * 32 + (t >> 3);
  const int dth = (t & 7) * 8;
  float l = 0.f;
#pragma unroll
  for (int s = 0; s < JSPLIT; ++s) l += lbuf[(size_t)s * ROWS_TOT + idx];
  float inv = 1.f / l;
  float o[8] = {0, 0, 0, 0, 0, 0, 0, 0};
#pragma unroll
  for (int s = 0; s < JSPLIT; ++s) {
    h8 v = *(const h8*)(Op + ((size_t)s * ROWS_TOT + idx) * HD + dth);
#pragma unroll
    for (int j = 0; j < 8; ++j) o[j] += (float)v[j];
  }
  const int bh = idx >> 10, row = idx & (CROP - 1);
  const int b = bh >> 3, h = bh & 7;
  short* dst = Ao + ((size_t)(b * CROP + row)) * NB + h * HD + dth;
  bf8 ov;
#pragma unroll
  for (int j = 0; j < 8; ++j) ov[j] = f2bf(o[j] * inv);
  *(bf8*)dst = ov;
}

// ---------------- output GEMM (bf16 in, fp32 out, BK=64) ----------------
__global__ __launch_bounds__(256) void out_gemm2(
    const short* __restrict__ A, const short* __restrict__ Wt,
    const float* __restrict__ Bb, float* __restrict__ Out)
{
  __shared__ short As[64][72];
  __shared__ short Bs[64][72];
  const int t = threadIdx.x;
  const int lane = t & 63, wave = t >> 6;
  const int wr = wave >> 1, wc = wave & 1;
  const int l15 = lane & 15, l4 = lane >> 4;
  const int bm = blockIdx.x, bn = blockIdx.y;

  f4 acc[2][2];
#pragma unroll
  for (int i = 0; i < 2; ++i)
#pragma unroll
    for (int j = 0; j < 2; ++j) acc[i][j] = (f4){0.f, 0.f, 0.f, 0.f};

  const int sr = t >> 2, sc = (t & 3) * 16;
  const short* arow = A + (size_t)(bm * 64 + sr) * NB + sc;
  const short* wrow = Wt + (size_t)(bn * 64 + sr) * NB + sc;

  for (int k0 = 0; k0 < NB; k0 += 64) {
    bf8 a0 = *(const bf8*)(arow + k0);
    bf8 a1 = *(const bf8*)(arow + k0 + 8);
    bf8 b0 = *(const bf8*)(wrow + k0);
    bf8 b1 = *(const bf8*)(wrow + k0 + 8);
    __syncthreads();
    *(bf8*)&As[sr][sc] = a0;
    *(bf8*)&As[sr][sc + 8] = a1;
    *(bf8*)&Bs[sr][sc] = b0;
    *(bf8*)&Bs[sr][sc + 8] = b1;
    __syncthreads();
#pragma unroll
    for (int ks = 0; ks < 2; ++ks) {
      bf8 af[2], bg[2];
#pragma unroll
      for (int mt = 0; mt < 2; ++mt)
        af[mt] = *(bf8*)&As[wr * 32 + mt * 16 + l15][ks * 32 + l4 * 8];
#pragma unroll
      for (int nt = 0; nt < 2; ++nt)
        bg[nt] = *(bf8*)&Bs[wc * 32 + nt * 16 + l15][ks * 32 + l4 * 8];
#pragma unroll
      for (int mt = 0; mt < 2; ++mt)
#pragma unroll
        for (int nt = 0; nt < 2; ++nt)
          acc[mt][nt] = mfma16(af[mt], bg[nt], acc[mt][nt]);
    }
  }
#pragma unroll
  for (int mt = 0; mt < 2; ++mt)
#pragma unroll
    for (int nt = 0; nt < 2; ++nt)
#pragma unroll
      for (int r = 0; r < 4; ++r) {
        int row = bm * 64 + wr * 32 + mt * 16 + l4 * 4 + r;
        int col = bn * 64 + wc * 32 + nt * 16 + l15;
        Out[(size_t)row * NB + col] = acc[mt][nt][r] + Bb[col];
      }
}

extern "C" void kernel_launch(void* const* d_in, const int* in_sizes, int n_in,
                              void* d_out, int out_size, void* d_ws, size_t ws_size,
                              hipStream_t stream) {
  (void)in_sizes; (void)n_in; (void)out_size; (void)ws_size;
  const float* x    = (const float*)d_in[0];
  const float* q_w  = (const float*)d_in[1];
  const float* q_b  = (const float*)d_in[2];
  const float* q_cw = (const float*)d_in[3];
  const float* q_cb = (const float*)d_in[4];
  const float* k_w  = (const float*)d_in[5];
  const float* k_b  = (const float*)d_in[6];
  const float* k_cw = (const float*)d_in[7];
  const float* k_cb = (const float*)d_in[8];
  const float* v_w  = (const float*)d_in[9];
  const float* v_b  = (const float*)d_in[10];
  const float* v_cw = (const float*)d_in[11];
  const float* v_cb = (const float*)d_in[12];
  const float* o_w  = (const float*)d_in[13];
  const float* o_b  = (const float*)d_in[14];
  const float* er   = (const float*)d_in[15];
  float* out = (float*)d_out;

  char* ws = (char*)d_ws;
  const size_t MB = 1u << 20;
  short* q0  = (short*)(ws + 0 * MB);
  short* k0  = (short*)(ws + 4 * MB);
  short* v0  = (short*)(ws + 8 * MB);
  short* qb2 = (short*)(ws + 12 * MB);
  short* kb2 = (short*)(ws + 16 * MB);
  short* vb2 = (short*)(ws + 20 * MB);
  short* ao  = (short*)(ws + 24 * MB);
  short* erT = (short*)(ws + 28 * MB);
  short* xb  = (short*)(ws + 29 * MB);
  short* wb  = (short*)(ws + 33 * MB);   // 4x512x512 bf16 = 2 MiB
  _Float16* Op = (_Float16*)(ws + 36 * MB);  // [4][32][1024][64] fp16 = 16 MiB
  float* lbuf  = (float*)(ws + 52 * MB);     // [4][32768] fp32 = 512 KiB

  ert_kernel<<<dim3(256), dim3(256), 0, stream>>>(er, erT);
  cvt_x_kernel<<<dim3(1024), dim3(256), 0, stream>>>(x, xb);
  cvt_w_kernel<<<dim3(128, 4), dim3(256), 0, stream>>>(q_w, k_w, v_w, o_w, wb);
  proj_gemm2<<<dim3(64, 8, 3), dim3(256), 0, stream>>>(
      xb, wb, q_b, k_b, v_b, q0, k0, v0);
  dwconv_qk<<<dim3(8192, 2), dim3(256), 0, stream>>>(
      q0, k0, q_cw, q_cb, k_cw, k_cb, qb2, kb2);
  dwconv_v<<<dim3(16, 8, 4), dim3(256), 0, stream>>>(v0, v_cw, v_cb, vb2);
  attn_part<<<dim3(8, NBH, JSPLIT), dim3(512), 0, stream>>>(
      qb2, kb2, vb2, erT, Op, lbuf);
  attn_combine<<<dim3(1024), dim3(256), 0, stream>>>(Op, lbuf, ao);
  out_gemm2<<<dim3(64, 8), dim3(256), 0, stream>>>(
      ao, wb + 3 * NB * NB, o_b, out);
}

// Round 5
// 71.161 us; speedup vs baseline: 1.7183x; 1.2257x over previous
//
#include <hip/hip_runtime.h>
#include <hip/hip_bf16.h>
#include <math.h>

// MultibandFrameAttention: B=4, W=1024, C=512, H=8, D=64
// R4b: same as R4 but with the exp2 device intrinsic fixed
//      (__exp2f -> __builtin_amdgcn_exp2f / inline-asm v_exp_f32).

#define CROP 1024
#define NB 512
#define NH 8
#define HD 64
#define NBATCH 4
#define MTOT 4096
#define NBH 32
#define JSPLIT 4
#define ROWS_TOT 32768  // NBH*CROP

typedef __attribute__((ext_vector_type(8))) short bf8;
typedef __attribute__((ext_vector_type(4))) float f4;
typedef __attribute__((ext_vector_type(8))) _Float16 h8;

__device__ __forceinline__ short f2bf(float f) {
  __hip_bfloat16 h = __float2bfloat16(f);
  short s;
  __builtin_memcpy(&s, &h, 2);
  return s;
}
__device__ __forceinline__ float bf2f(short s) {
  union { unsigned u; float f; } v; v.u = ((unsigned)(unsigned short)s) << 16;
  return v.f;
}
__device__ __forceinline__ f4 mfma16(bf8 a, bf8 b, f4 c) {
  return __builtin_amdgcn_mfma_f32_16x16x32_bf16(a, b, c, 0, 0, 0);
}
__device__ __forceinline__ float fast_exp2(float x) {
#if __has_builtin(__builtin_amdgcn_exp2f)
  return __builtin_amdgcn_exp2f(x);
#else
  float r;
  asm("v_exp_f32 %0, %1" : "=v"(r) : "v"(x));
  return r;
#endif
}

#define ISC 0.044194173824159216f        // 1/sqrt(512)
#define QSCALE 0.06376743237228177f      // ISC * log2(e)

// ---------------- fused prep: cvt_x | cvt_w x4 | er transpose ----------------
__global__ __launch_bounds__(256) void prep_kernel(
    const float* __restrict__ x,
    const float* __restrict__ w0, const float* __restrict__ w1,
    const float* __restrict__ w2, const float* __restrict__ w3,
    const float* __restrict__ er,
    short* __restrict__ xb, short* __restrict__ wb, short* __restrict__ erT)
{
  const int blk = blockIdx.x;
  const int t = threadIdx.x;
  if (blk < 1024) {  // cvt_x: 2M elems, 8/thread
    int i = (blk * 256 + t) * 8;
    f4 a = *(const f4*)(x + i);
    f4 b = *(const f4*)(x + i + 4);
    bf8 o;
#pragma unroll
    for (int j = 0; j < 4; ++j) { o[j] = f2bf(a[j]); o[4 + j] = f2bf(b[j]); }
    *(bf8*)(xb + i) = o;
  } else if (blk < 1536) {  // cvt_w: 4 x 256K elems, 8/thread, 128 blocks each
    int p = (blk - 1024) >> 7;
    const float* s = (p == 0) ? w0 : (p == 1) ? w1 : (p == 2) ? w2 : w3;
    int i = (((blk - 1024) & 127) * 256 + t) * 8;
    f4 a = *(const f4*)(s + i);
    f4 b = *(const f4*)(s + i + 4);
    bf8 o;
#pragma unroll
    for (int j = 0; j < 4; ++j) { o[j] = f2bf(a[j]); o[4 + j] = f2bf(b[j]); }
    *(bf8*)(wb + (size_t)p * NB * NB + i) = o;
  } else {  // ert: 64K elems, 1/thread
    int idx = (blk - 1536) * 256 + t;
    int w = idx >> 6, d = idx & 63;
    erT[idx] = f2bf(er[d * CROP + w]);
  }
}

// ---------------- QKV projection GEMM (bf16 in, BK=64) ----------------
__global__ __launch_bounds__(256) void proj_gemm2(
    const short* __restrict__ Xb, const short* __restrict__ Wb,
    const float* __restrict__ B0, const float* __restrict__ B1, const float* __restrict__ B2,
    short* __restrict__ O0, short* __restrict__ O1, short* __restrict__ O2)
{
  const int p = blockIdx.z;
  const short* Wt = Wb + (size_t)p * NB * NB;
  const float* Bb = (p == 0) ? B0 : (p == 1) ? B1 : B2;
  short* Out = (p == 0) ? O0 : (p == 1) ? O1 : O2;

  __shared__ short As[64][72];
  __shared__ short Bs[64][72];

  const int t = threadIdx.x;
  const int lane = t & 63, wave = t >> 6;
  const int wr = wave >> 1, wc = wave & 1;
  const int l15 = lane & 15, l4 = lane >> 4;
  const int bm = blockIdx.x, bn = blockIdx.y;

  f4 acc[2][2];
#pragma unroll
  for (int i = 0; i < 2; ++i)
#pragma unroll
    for (int j = 0; j < 2; ++j) acc[i][j] = (f4){0.f, 0.f, 0.f, 0.f};

  const int sr = t >> 2, sc = (t & 3) * 16;
  const short* xrow = Xb + (size_t)(bm * 64 + sr) * NB + sc;
  const short* wrow = Wt + (size_t)(bn * 64 + sr) * NB + sc;

  for (int k0 = 0; k0 < NB; k0 += 64) {
    bf8 a0 = *(const bf8*)(xrow + k0);
    bf8 a1 = *(const bf8*)(xrow + k0 + 8);
    bf8 b0 = *(const bf8*)(wrow + k0);
    bf8 b1 = *(const bf8*)(wrow + k0 + 8);
    __syncthreads();
    *(bf8*)&As[sr][sc] = a0;
    *(bf8*)&As[sr][sc + 8] = a1;
    *(bf8*)&Bs[sr][sc] = b0;
    *(bf8*)&Bs[sr][sc + 8] = b1;
    __syncthreads();
#pragma unroll
    for (int ks = 0; ks < 2; ++ks) {
      bf8 af[2], bg[2];
#pragma unroll
      for (int mt = 0; mt < 2; ++mt)
        af[mt] = *(bf8*)&As[wr * 32 + mt * 16 + l15][ks * 32 + l4 * 8];
#pragma unroll
      for (int nt = 0; nt < 2; ++nt)
        bg[nt] = *(bf8*)&Bs[wc * 32 + nt * 16 + l15][ks * 32 + l4 * 8];
#pragma unroll
      for (int mt = 0; mt < 2; ++mt)
#pragma unroll
        for (int nt = 0; nt < 2; ++nt)
          acc[mt][nt] = mfma16(af[mt], bg[nt], acc[mt][nt]);
    }
  }
#pragma unroll
  for (int mt = 0; mt < 2; ++mt)
#pragma unroll
    for (int nt = 0; nt < 2; ++nt)
#pragma unroll
      for (int r = 0; r < 4; ++r) {
        int row = bm * 64 + wr * 32 + mt * 16 + l4 * 4 + r;
        int col = bn * 64 + wc * 32 + nt * 16 + l15;
        Out[(size_t)row * NB + col] = f2bf(acc[mt][nt][r] + Bb[col]);
      }
}

// ---------------- fused depthwise conv: q (scaled), k -> [b,h,w,d]; v -> [b*c][w] ----------------
__global__ __launch_bounds__(256) void dwconv_all(
    const short* __restrict__ q0p, const short* __restrict__ k0p,
    const short* __restrict__ v0p,
    const float* __restrict__ qcw, const float* __restrict__ qcb,
    const float* __restrict__ kcw, const float* __restrict__ kcb,
    const float* __restrict__ vcw, const float* __restrict__ vcb,
    short* __restrict__ qb, short* __restrict__ kb, short* __restrict__ vb)
{
  const int blk = blockIdx.x;
  const int t = threadIdx.x;

  if (blk < 2048) {
    // ---- q/k path: 8 channels per thread, vectorized ----
    const int p = blk >> 10;
    const short* src = p ? k0p : q0p;
    const float* cw = p ? kcw : qcw;
    const float* cb = p ? kcb : qcb;
    short* dst = p ? kb : qb;
    const float scale = p ? 1.0f : QSCALE;

    const int idx = ((blk & 1023) * 256 + t) * 8;  // elem base, c-aligned-8
    const int c = idx & (NB - 1);
    const int m = idx >> 9;
    const int w = m & (CROP - 1);
    const int b = m >> 10;

    const bf8 z = (bf8){0, 0, 0, 0, 0, 0, 0, 0};
    bf8 mid = *(const bf8*)(src + idx);
    bf8 lo = (w > 0) ? *(const bf8*)(src + idx - NB) : z;
    bf8 hi = (w < CROP - 1) ? *(const bf8*)(src + idx + NB) : z;

    f4 cwv[6];
#pragma unroll
    for (int i = 0; i < 6; ++i) cwv[i] = *(const f4*)(cw + c * 3 + i * 4);
    f4 cb0 = *(const f4*)(cb + c);
    f4 cb1 = *(const f4*)(cb + c + 4);

    bf8 o;
#pragma unroll
    for (int j = 0; j < 8; ++j) {
      float k0w = cwv[(3 * j) >> 2][(3 * j) & 3];
      float k1w = cwv[(3 * j + 1) >> 2][(3 * j + 1) & 3];
      float k2w = cwv[(3 * j + 2) >> 2][(3 * j + 2) & 3];
      float bias = (j < 4) ? cb0[j] : cb1[j - 4];
      float acc = bias + k0w * bf2f(lo[j]) + k1w * bf2f(mid[j]) + k2w * bf2f(hi[j]);
      o[j] = f2bf(acc * scale);
    }
    const int h = c >> 6, d0 = c & 63;
    *(bf8*)(dst + ((size_t)(b * NH + h) * CROP + w) * HD + d0) = o;
  } else {
    // ---- v path: LDS-staged transpose ----
    __shared__ short S[66][72];
    const int blk2 = blk - 2048;
    const int w0 = (blk2 & 15) * 64, c0 = ((blk2 >> 4) & 7) * 64, b = blk2 >> 7;

#pragma unroll
    for (int i = 0; i < 3; ++i) {
      int r = i * 32 + (t >> 3);
      if (r < 66) {
        int w = w0 - 1 + r;
        int cg = (t & 7) * 8;
        bf8 val = (bf8){0, 0, 0, 0, 0, 0, 0, 0};
        if (w >= 0 && w < CROP)
          val = *(const bf8*)(v0p + ((size_t)b * CROP + w) * NB + c0 + cg);
        *(bf8*)&S[r][cg] = val;
      }
    }
    __syncthreads();

    const int c = t & 63, wv = t >> 6;
    const float k0w = vcw[(c0 + c) * 3 + 0];
    const float k1w = vcw[(c0 + c) * 3 + 1];
    const float k2w = vcw[(c0 + c) * 3 + 2];
    const float bias = vcb[c0 + c];

    float xa = bf2f(S[wv * 16][c]);
    float xb2 = bf2f(S[wv * 16 + 1][c]);
    short res[16];
#pragma unroll
    for (int ww = 0; ww < 16; ++ww) {
      float xc = bf2f(S[wv * 16 + ww + 2][c]);
      res[ww] = f2bf(bias + k0w * xa + k1w * xb2 + k2w * xc);
      xa = xb2; xb2 = xc;
    }
    short* dst = vb + ((size_t)(b * NB) + c0 + c) * CROP + w0 + wv * 16;
    *(bf8*)dst = *(bf8*)&res[0];
    *(bf8*)(dst + 8) = *(bf8*)&res[8];
  }
}

// ---------------- flash attention partial (split-j, no-max, exp2) ----------------
// blockIdx: x = qt (8 x 128 rows), y = bh (32), z = s (JSPLIT)
__global__ __launch_bounds__(512) void attn_part(
    const short* __restrict__ Qb, const short* __restrict__ Kb,
    const short* __restrict__ Vb, const short* __restrict__ ErT,
    _Float16* __restrict__ Op, float* __restrict__ lbuf)
{
  __shared__ short Ks[64][72];
  __shared__ short Qs[64][72];
  __shared__ short Vs[64][72];
  __shared__ short Ps[8][16][72];

  const int qt = blockIdx.x, bh = blockIdx.y, s = blockIdx.z;
  const int t = threadIdx.x;
  const int lane = t & 63, wave = t >> 6;
  const int l15 = lane & 15, l4 = lane >> 4;
  const int wq = qt * 128 + wave * 16;

  bf8 qa[2], ea[2];
  {
    const short* qrow = Qb + ((size_t)bh * CROP + wq + l15) * HD + l4 * 8;
    qa[0] = *(const bf8*)(qrow);
    qa[1] = *(const bf8*)(qrow + 32);
    const short* erow = ErT + (size_t)(wq + l15) * HD + l4 * 8;
    ea[0] = *(const bf8*)(erow);
    ea[1] = *(const bf8*)(erow + 32);
  }

  float lsum[4] = {0.f, 0.f, 0.f, 0.f};
  f4 oacc[4];
#pragma unroll
  for (int nt = 0; nt < 4; ++nt) oacc[nt] = (f4){0.f, 0.f, 0.f, 0.f};

  const int sr2 = t >> 3, sc2 = (t & 7) * 8;
  const short* ksrc = Kb + ((size_t)bh * CROP + sr2) * HD + sc2;
  const short* qsrc = Qb + ((size_t)bh * CROP + sr2) * HD + sc2;
  const short* vsrc = Vb + ((size_t)bh * HD + sr2) * CROP + sc2;

  const int jbase = s * (CROP / JSPLIT);
  const int JLEN = CROP / JSPLIT;

  // T14: prefetch tile 0 into regs
  bf8 rk = *(const bf8*)(ksrc + jbase * HD);
  bf8 rq = *(const bf8*)(qsrc + jbase * HD);
  bf8 rv = *(const bf8*)(vsrc + jbase);

  for (int jj = 0; jj < JLEN; jj += 64) {
    __syncthreads();
    *(bf8*)&Ks[sr2][sc2] = rk;
    *(bf8*)&Qs[sr2][sc2] = rq;
    *(bf8*)&Vs[sr2][sc2] = rv;
    __syncthreads();

    // issue next tile's loads now; they complete under the compute below
    const int jn = jj + 64;
    if (jn < JLEN) {
      rk = *(const bf8*)(ksrc + (jbase + jn) * HD);
      rq = *(const bf8*)(qsrc + (jbase + jn) * HD);
      rv = *(const bf8*)(vsrc + jbase + jn);
    }

    // S tile [16 rows][64 j] = (Q*qscale)_I K_J^T + erT_I (Q*qscale)_J^T
    f4 sacc[4];
#pragma unroll
    for (int nt = 0; nt < 4; ++nt) sacc[nt] = (f4){0.f, 0.f, 0.f, 0.f};
    __builtin_amdgcn_s_setprio(1);
#pragma unroll
    for (int ks = 0; ks < 2; ++ks) {
#pragma unroll
      for (int nt = 0; nt < 4; ++nt) {
        bf8 kf = *(bf8*)&Ks[nt * 16 + l15][ks * 32 + l4 * 8];
        sacc[nt] = mfma16(qa[ks], kf, sacc[nt]);
        bf8 qf = *(bf8*)&Qs[nt * 16 + l15][ks * 32 + l4 * 8];
        sacc[nt] = mfma16(ea[ks], qf, sacc[nt]);
      }
    }
    __builtin_amdgcn_s_setprio(0);

    // P = exp2(S) (log2e pre-folded into Q); per-lane row sums; P -> LDS
#pragma unroll
    for (int r = 0; r < 4; ++r) {
      const int prow = l4 * 4 + r;
      float pv0 = fast_exp2(sacc[0][r]);
      float pv1 = fast_exp2(sacc[1][r]);
      float pv2 = fast_exp2(sacc[2][r]);
      float pv3 = fast_exp2(sacc[3][r]);
      lsum[r] += (pv0 + pv1) + (pv2 + pv3);
      Ps[wave][prow][0 * 16 + l15] = f2bf(pv0);
      Ps[wave][prow][1 * 16 + l15] = f2bf(pv1);
      Ps[wave][prow][2 * 16 + l15] = f2bf(pv2);
      Ps[wave][prow][3 * 16 + l15] = f2bf(pv3);
    }

    __builtin_amdgcn_s_setprio(1);
#pragma unroll
    for (int ks = 0; ks < 2; ++ks) {
      bf8 pf = *(bf8*)&Ps[wave][l15][ks * 32 + l4 * 8];
#pragma unroll
      for (int nt = 0; nt < 4; ++nt) {
        bf8 vf = *(bf8*)&Vs[nt * 16 + l15][ks * 32 + l4 * 8];
        oacc[nt] = mfma16(pf, vf, oacc[nt]);
      }
    }
    __builtin_amdgcn_s_setprio(0);
  }

  // reduce row sums across the 16 lanes sharing each row
#pragma unroll
  for (int r = 0; r < 4; ++r) {
#pragma unroll
    for (int off = 1; off < 16; off <<= 1)
      lsum[r] += __shfl_xor(lsum[r], off);
  }

#pragma unroll
  for (int r = 0; r < 4; ++r) {
    const int row = wq + l4 * 4 + r;
    const size_t ridx = (size_t)(s * NBH + bh) * CROP + row;
#pragma unroll
    for (int nt = 0; nt < 4; ++nt)
      Op[ridx * HD + nt * 16 + l15] = (_Float16)oacc[nt][r];
    if (l15 == 0) lbuf[ridx] = lsum[r];
  }
}

// ---------------- combine partials -> ao [b*1024+w][512] bf16 ----------------
__global__ __launch_bounds__(256) void attn_combine(
    const _Float16* __restrict__ Op, const float* __restrict__ lbuf,
    short* __restrict__ Ao)
{
  const int t = threadIdx.x;
  const int idx = blockIdx.x * 32 + (t >> 3);
  const int dth = (t & 7) * 8;
  float l = 0.f;
#pragma unroll
  for (int s = 0; s < JSPLIT; ++s) l += lbuf[(size_t)s * ROWS_TOT + idx];
  float inv = 1.f / l;
  float o[8] = {0, 0, 0, 0, 0, 0, 0, 0};
#pragma unroll
  for (int s = 0; s < JSPLIT; ++s) {
    h8 v = *(const h8*)(Op + ((size_t)s * ROWS_TOT + idx) * HD + dth);
#pragma unroll
    for (int j = 0; j < 8; ++j) o[j] += (float)v[j];
  }
  const int bh = idx >> 10, row = idx & (CROP - 1);
  const int b = bh >> 3, h = bh & 7;
  short* dst = Ao + ((size_t)(b * CROP + row)) * NB + h * HD + dth;
  bf8 ov;
#pragma unroll
  for (int j = 0; j < 8; ++j) ov[j] = f2bf(o[j] * inv);
  *(bf8*)dst = ov;
}

// ---------------- output GEMM (bf16 in, fp32 out, BK=64) ----------------
__global__ __launch_bounds__(256) void out_gemm2(
    const short* __restrict__ A, const short* __restrict__ Wt,
    const float* __restrict__ Bb, float* __restrict__ Out)
{
  __shared__ short As[64][72];
  __shared__ short Bs[64][72];
  const int t = threadIdx.x;
  const int lane = t & 63, wave = t >> 6;
  const int wr = wave >> 1, wc = wave & 1;
  const int l15 = lane & 15, l4 = lane >> 4;
  const int bm = blockIdx.x, bn = blockIdx.y;

  f4 acc[2][2];
#pragma unroll
  for (int i = 0; i < 2; ++i)
#pragma unroll
    for (int j = 0; j < 2; ++j) acc[i][j] = (f4){0.f, 0.f, 0.f, 0.f};

  const int sr = t >> 2, sc = (t & 3) * 16;
  const short* arow = A + (size_t)(bm * 64 + sr) * NB + sc;
  const short* wrow = Wt + (size_t)(bn * 64 + sr) * NB + sc;

  for (int k0 = 0; k0 < NB; k0 += 64) {
    bf8 a0 = *(const bf8*)(arow + k0);
    bf8 a1 = *(const bf8*)(arow + k0 + 8);
    bf8 b0 = *(const bf8*)(wrow + k0);
    bf8 b1 = *(const bf8*)(wrow + k0 + 8);
    __syncthreads();
    *(bf8*)&As[sr][sc] = a0;
    *(bf8*)&As[sr][sc + 8] = a1;
    *(bf8*)&Bs[sr][sc] = b0;
    *(bf8*)&Bs[sr][sc + 8] = b1;
    __syncthreads();
#pragma unroll
    for (int ks = 0; ks < 2; ++ks) {
      bf8 af[2], bg[2];
#pragma unroll
      for (int mt = 0; mt < 2; ++mt)
        af[mt] = *(bf8*)&As[wr * 32 + mt * 16 + l15][ks * 32 + l4 * 8];
#pragma unroll
      for (int nt = 0; nt < 2; ++nt)
        bg[nt] = *(bf8*)&Bs[wc * 32 + nt * 16 + l15][ks * 32 + l4 * 8];
#pragma unroll
      for (int mt = 0; mt < 2; ++mt)
#pragma unroll
        for (int nt = 0; nt < 2; ++nt)
          acc[mt][nt] = mfma16(af[mt], bg[nt], acc[mt][nt]);
    }
  }
#pragma unroll
  for (int mt = 0; mt < 2; ++mt)
#pragma unroll
    for (int nt = 0; nt < 2; ++nt)
#pragma unroll
      for (int r = 0; r < 4; ++r) {
        int row = bm * 64 + wr * 32 + mt * 16 + l4 * 4 + r;
        int col = bn * 64 + wc * 32 + nt * 16 + l15;
        Out[(size_t)row * NB + col] = acc[mt][nt][r] + Bb[col];
      }
}

extern "C" void kernel_launch(void* const* d_in, const int* in_sizes, int n_in,
                              void* d_out, int out_size, void* d_ws, size_t ws_size,
                              hipStream_t stream) {
  (void)in_sizes; (void)n_in; (void)out_size; (void)ws_size;
  const float* x    = (const float*)d_in[0];
  const float* q_w  = (const float*)d_in[1];
  const float* q_b  = (const float*)d_in[2];
  const float* q_cw = (const float*)d_in[3];
  const float* q_cb = (const float*)d_in[4];
  const float* k_w  = (const float*)d_in[5];
  const float* k_b  = (const float*)d_in[6];
  const float* k_cw = (const float*)d_in[7];
  const float* k_cb = (const float*)d_in[8];
  const float* v_w  = (const float*)d_in[9];
  const float* v_b  = (const float*)d_in[10];
  const float* v_cw = (const float*)d_in[11];
  const float* v_cb = (const float*)d_in[12];
  const float* o_w  = (const float*)d_in[13];
  const float* o_b  = (const float*)d_in[14];
  const float* er   = (const float*)d_in[15];
  float* out = (float*)d_out;

  char* ws = (char*)d_ws;
  const size_t MB = 1u << 20;
  short* q0  = (short*)(ws + 0 * MB);
  short* k0  = (short*)(ws + 4 * MB);
  short* v0  = (short*)(ws + 8 * MB);
  short* qb2 = (short*)(ws + 12 * MB);
  short* kb2 = (short*)(ws + 16 * MB);
  short* vb2 = (short*)(ws + 20 * MB);
  short* ao  = (short*)(ws + 24 * MB);
  short* erT = (short*)(ws + 28 * MB);
  short* xb  = (short*)(ws + 29 * MB);
  short* wb  = (short*)(ws + 33 * MB);       // 4x512x512 bf16 = 2 MiB
  _Float16* Op = (_Float16*)(ws + 36 * MB);  // [4][32][1024][64] fp16 = 16 MiB
  float* lbuf  = (float*)(ws + 52 * MB);     // [4][32768] fp32 = 512 KiB

  prep_kernel<<<dim3(1792), dim3(256), 0, stream>>>(
      x, q_w, k_w, v_w, o_w, er, xb, wb, erT);
  proj_gemm2<<<dim3(64, 8, 3), dim3(256), 0, stream>>>(
      xb, wb, q_b, k_b, v_b, q0, k0, v0);
  dwconv_all<<<dim3(2560), dim3(256), 0, stream>>>(
      q0, k0, v0, q_cw, q_cb, k_cw, k_cb, v_cw, v_cb, qb2, kb2, vb2);
  attn_part<<<dim3(8, NBH, JSPLIT), dim3(512), 0, stream>>>(
      qb2, kb2, vb2, erT, Op, lbuf);
  attn_combine<<<dim3(1024), dim3(256), 0, stream>>>(Op, lbuf, ao);
  out_gemm2<<<dim3(64, 8), dim3(256), 0, stream>>>(
      ao, wb + 3 * NB * NB, o_b, out);
}